// Round 15
// baseline (129.260 us; speedup 1.0000x reference)
//
#include <hip/hip_runtime.h>
#include <hip/hip_bf16.h>
#include <stdint.h>
#include <stddef.h>

typedef __attribute__((ext_vector_type(8))) __bf16 bf16x8;
typedef __attribute__((ext_vector_type(4))) float f32x4;

#define DMODEL 1024
#define HEADS  16
#define BATCH  4
#define TSEQ   2048
#define MROWS  (BATCH * TSEQ)   // 8192
#define NE     (MROWS * DMODEL) // 8388608
#define NW     (DMODEL * DMODEL)

#define MiB (size_t)1048576
// no enc/dec conversion buffers anymore: GEMM reads f32 A directly.
#define QB_OFF   ((size_t)0)          // 16 MiB bf16
#define KB_OFF   (16 * MiB)           // 16 MiB bf16
#define VB_OFF   (32 * MiB)           // 16 MiB bf16
#define KVP_OFF  (48 * MiB)           // 4 MiB f32 partials
#define WB_OFF   (52 * MiB)           // 6 MiB bf16 (Wq,Wk,Wv)
#define KVT_OFF  (58 * MiB)           // 512 KiB bf16

// ---------------------------------------------------------------------------
// weights f32 -> bf16 (14 MB traffic, ~2.5us). enc/dec stay f32: the GEMM
// stages A as f32 and converts at the LDS-READ side (r5/r11 failures were
// STAGE-side conversion - VALU/issue-bound; read-side rides MFMA slack).
// ---------------------------------------------------------------------------
__global__ __launch_bounds__(256)
void conv_w(const float* __restrict__ Wq, const float* __restrict__ Wk,
            const float* __restrict__ Wv, __bf16* __restrict__ WB)
{
    const int bid = blockIdx.x;            // 0..1535
    const int sel = bid >> 9, blk = bid & 511;
    const float* src = (sel == 0) ? Wq : (sel == 1) ? Wk : Wv;
    const int i = blk * 2048 + threadIdx.x * 8;
    f32x4 a = *(const f32x4*)(src + i);
    f32x4 b = *(const f32x4*)(src + i + 4);
    bf16x8 o;
#pragma unroll
    for (int j = 0; j < 4; ++j) { o[j] = (__bf16)a[j]; o[j + 4] = (__bf16)b[j]; }
    *(bf16x8*)&WB[(size_t)sel * NW + i] = o;
}

// ---------------------------------------------------------------------------
// Fused QKV GEMM — r9/r14 skeleton (banked best) with f32 A operand:
// BM=128, BN=256, BK=64, 8 waves (2Mx4N), merged K-tile phases, double
// barrier KPHASE, counted VMW(8) (8 gloads/thread/tile: A=4 f32 + B=4).
// A staged as f32 via global_load_lds (128 rows x 16 16B-slots, swizzle
// slot^(row&15) on BOTH source and read -> 2 lanes/bank = free); A-frag
// read = 2x ds_read_b128 + packed casts (same RNE as conv_all -> absmax
// bit-identical). B path byte-identical to r14. LDS 64K(A f32)+64K(B).
// Grid 768 = 8 slabs x (8 bm x 12 (sel,bn)) = 3 exact CU rounds (T1).
// ---------------------------------------------------------------------------
__device__ __forceinline__ bf16x8 fragB(const __bf16* reg, int rowl, int kh, int g4)
{
    const int slot = ((kh << 2) + g4) ^ (rowl & 7);
    return *(const bf16x8*)(reg + rowl * 64 + slot * 8);
}

__device__ __forceinline__ bf16x8 fragA32(const float* buf, int rowl, int kh, int g4)
{
    const int s0 = kh * 8 + g4 * 2;             // logical 16B slot (even)
    const float* base = buf + rowl * 64;
    f32x4 a = *(const f32x4*)(base + ((s0 ^ (rowl & 15)) << 2));
    f32x4 b = *(const f32x4*)(base + (((s0 + 1) ^ (rowl & 15)) << 2));
    bf16x8 o;
#pragma unroll
    for (int j = 0; j < 4; ++j) { o[j] = (__bf16)a[j]; o[j + 4] = (__bf16)b[j]; }
    return o;
}

// stage one 128x64(f32) A-tile: 2048 x 16B chunks, 4 per thread
__device__ __forceinline__ void stageA32(const float* gbase, int kt,
                                         float* reg, int tid)
{
#pragma unroll
    for (int p = 0; p < 4; ++p) {
        const int c = tid + p * 512;
        const int row = c >> 4, slot = c & 15;
        const float* src = gbase + (size_t)row * DMODEL + kt * 64
                           + ((slot ^ (row & 15)) << 2);
        __builtin_amdgcn_global_load_lds(
            (const __attribute__((address_space(1))) void*)src,
            (__attribute__((address_space(3))) void*)(reg + c * 4), 16, 0, 0);
    }
}

__device__ __forceinline__ void stage_halfB(const __bf16* gbase, int kt,
                                            __bf16* reg, int tid)
{
#pragma unroll
    for (int p = 0; p < 2; ++p) {
        const int c = tid + p * 512;
        const int row = c >> 3, slot = c & 7;
        const __bf16* src = gbase + (size_t)row * DMODEL + kt * 64
                            + ((slot ^ (row & 7)) << 3);
        __builtin_amdgcn_global_load_lds(
            (const __attribute__((address_space(1))) void*)src,
            (__attribute__((address_space(3))) void*)(reg + c * 8), 16, 0, 0);
    }
}

#define VMW(N)  asm volatile("s_waitcnt vmcnt(" #N ")" ::: "memory")
#define LGKM0() asm volatile("s_waitcnt lgkmcnt(0)" ::: "memory")

#define KPHASE(PAR, STAGE_CODE, WAIT_CODE)                                    \
  {                                                                           \
    bf16x8 af[4][2], bfv[4][2];                                               \
    _Pragma("unroll") for (int mf = 0; mf < 4; ++mf)                          \
      _Pragma("unroll") for (int kh = 0; kh < 2; ++kh)                        \
        af[mf][kh] = fragA32(&ldsAf[(PAR) * 8192], wm * 64 + mf * 16 + l4, kh, g4); \
    _Pragma("unroll") for (int nf = 0; nf < 4; ++nf)                          \
      _Pragma("unroll") for (int kh = 0; kh < 2; ++kh)                        \
        bfv[nf][kh] = fragB(&ldsB[(PAR) * 16384 + bh2 * 8192],                \
                            (wn & 1) * 64 + nf * 16 + l4, kh, g4);            \
    LGKM0();                                                                  \
    __builtin_amdgcn_sched_barrier(0);                                        \
    __builtin_amdgcn_s_barrier();                                             \
    STAGE_CODE;                                                               \
    __builtin_amdgcn_sched_barrier(0);                                        \
    __builtin_amdgcn_s_setprio(1);                                            \
    _Pragma("unroll") for (int mf = 0; mf < 4; ++mf)                          \
      _Pragma("unroll") for (int nf = 0; nf < 4; ++nf)                        \
        _Pragma("unroll") for (int kh = 0; kh < 2; ++kh)                      \
          acc[mf][nf] = __builtin_amdgcn_mfma_f32_16x16x32_bf16(              \
              af[mf][kh], bfv[nf][kh], acc[mf][nf], 0, 0, 0);                 \
    __builtin_amdgcn_s_setprio(0);                                            \
    WAIT_CODE;                                                                \
    __builtin_amdgcn_s_barrier();                                             \
  }

__global__ __launch_bounds__(512, 2)
void qkv_gemm(const float* __restrict__ dec, const float* __restrict__ enc,
              const __bf16* __restrict__ WB,
              const float* __restrict__ bq, const float* __restrict__ bk,
              const float* __restrict__ bv,
              __bf16* __restrict__ Qb, __bf16* __restrict__ Kb,
              __bf16* __restrict__ Vb)
{
    __shared__ __align__(16) float  ldsAf[2 * 8192];   // [parity][128x64 f32] 64K
    __shared__ __align__(16) __bf16 ldsB[2 * 16384];   // [parity][2 halves]   64K

    const int tid  = threadIdx.x;
    const int lane = tid & 63;
    const int wv   = tid >> 6;
    const int wm   = wv >> 2;
    const int wn   = wv & 3;
    const int bh2  = wn >> 1;
    const int l4   = lane & 15;
    const int g4   = lane >> 4;

    const int bid  = blockIdx.x;
    const int slab = bid & 7;
    const int idx  = bid >> 3;
    const int r    = idx >> 3;
    const int sel  = r >> 2;
    const int bn   = r & 3;
    const int bm   = slab * 8 + (idx & 7);

    const float*  A    = (sel == 0) ? dec : enc;
    const __bf16* Wb   = WB + (size_t)sel * NW + (size_t)(bn * 256) * DMODEL;
    const float*  bias = (sel == 0) ? bq : (sel == 1) ? bk : bv;
    __bf16*       C    = (sel == 0) ? Qb : (sel == 1) ? Kb : Vb;

    const float* Ab = A + (size_t)(bm * 128) * DMODEL;

    auto stage_tile = [&](int par, int kt) {
        stageA32(Ab, kt, ldsAf + par * 8192, tid);                            // 4
        stage_halfB(Wb,                        kt, ldsB + par * 16384,        tid); // 2
        stage_halfB(Wb + (size_t)128 * DMODEL, kt, ldsB + par * 16384 + 8192, tid); // 2
    };

    f32x4 acc[4][4] = {};

    stage_tile(0, 0);
    stage_tile(1, 1);
    VMW(8);
    __builtin_amdgcn_sched_barrier(0);
    __builtin_amdgcn_s_barrier();

    for (int i = 0; i < 8; ++i) {      // 16 K-tiles, 2 per iter
        KPHASE(0, { if (i < 7) stage_tile(0, 2 * i + 2); },
                  { if (i < 7) { VMW(8); } else { VMW(0); } })
        KPHASE(1, { if (i < 7) stage_tile(1, 2 * i + 3); },
                  { if (i < 7) { VMW(8); } else { VMW(0); } })
    }

#pragma unroll
    for (int mf = 0; mf < 4; ++mf)
#pragma unroll
        for (int nf = 0; nf < 4; ++nf) {
            const int gm0 = bm * 128 + wm * 64 + mf * 16 + g4 * 4;
            const int gn  = bn * 256 + wn * 64 + nf * 16 + l4;
            const float bv2 = bias[gn];
#pragma unroll
            for (int j = 0; j < 4; ++j)
                C[(size_t)(gm0 + j) * DMODEL + gn] =
                    (__bf16)(acc[mf][nf][j] + bv2);
        }
}

// ---------------------------------------------------------------------------
// kv partials + in-block cross-wave reduction (r14-verified)
// ---------------------------------------------------------------------------
__global__ __launch_bounds__(256)
void kv_mm(const __bf16* __restrict__ Kb, const __bf16* __restrict__ Vb,
           float* __restrict__ kvp)
{
    __shared__ __align__(16) float Ks[128][64];
    __shared__ __align__(16) float Vs[128][64];

    const int tid = threadIdx.x;
    const int bh  = blockIdx.x;
    const int ch  = blockIdx.y;
    const int b   = bh >> 4, h = bh & 15;
    const int w   = tid >> 6, lane = tid & 63;
    const int dg  = (lane >> 3) * 8;
    const int eg  = (lane & 7) * 8;
    const size_t base = (size_t)b * TSEQ + (size_t)ch * 512;

    f32x4 acc[8][2] = {};

    for (int ss = 0; ss < 4; ++ss) {
        __syncthreads();
#pragma unroll
        for (int i = 0; i < 4; ++i) {
            const int e = i * 2048 + tid * 8;
            const int t = e >> 6, d = e & 63;
            bf16x8 k8 = *(const bf16x8*)&Kb[(base + ss * 128 + t) * DMODEL + h * 64 + d];
            bf16x8 v8 = *(const bf16x8*)&Vb[(base + ss * 128 + t) * DMODEL + h * 64 + d];
            f32x4 kf0, kf1, vf0, vf1;
#pragma unroll
            for (int j = 0; j < 4; ++j) {
                kf0[j] = (float)k8[j]; kf1[j] = (float)k8[j + 4];
                vf0[j] = (float)v8[j]; vf1[j] = (float)v8[j + 4];
            }
            *(f32x4*)&Ks[t][d]     = kf0;
            *(f32x4*)&Ks[t][d + 4] = kf1;
            *(f32x4*)&Vs[t][d]     = vf0;
            *(f32x4*)&Vs[t][d + 4] = vf1;
        }
        __syncthreads();

#pragma unroll 4
        for (int tt = 0; tt < 32; ++tt) {
            const int t = w * 32 + tt;
            f32x4 kd0 = *(const f32x4*)&Ks[t][dg];
            f32x4 kd1 = *(const f32x4*)&Ks[t][dg + 4];
            f32x4 ve0 = *(const f32x4*)&Vs[t][eg];
            f32x4 ve1 = *(const f32x4*)&Vs[t][eg + 4];
#pragma unroll
            for (int rr = 0; rr < 8; ++rr) {
                const float kd = (rr < 4) ? kd0[rr] : kd1[rr - 4];
                acc[rr][0] += ve0 * kd;
                acc[rr][1] += ve1 * kd;
            }
        }
    }

    float* red = &Ks[0][0];
    __syncthreads();
    if (w >= 2) {
        float* dstw = red + (w - 2) * 4096 + dg * 64 + eg;
#pragma unroll
        for (int rr = 0; rr < 8; ++rr) {
            *(f32x4*)(dstw + rr * 64)     = acc[rr][0];
            *(f32x4*)(dstw + rr * 64 + 4) = acc[rr][1];
        }
    }
    __syncthreads();
    if (w < 2) {
        const float* srcw = red + w * 4096 + dg * 64 + eg;
#pragma unroll
        for (int rr = 0; rr < 8; ++rr) {
            acc[rr][0] += *(const f32x4*)(srcw + rr * 64);
            acc[rr][1] += *(const f32x4*)(srcw + rr * 64 + 4);
        }
    }
    __syncthreads();
    if (w == 1) {
        float* dstw = red + dg * 64 + eg;
#pragma unroll
        for (int rr = 0; rr < 8; ++rr) {
            *(f32x4*)(dstw + rr * 64)     = acc[rr][0];
            *(f32x4*)(dstw + rr * 64 + 4) = acc[rr][1];
        }
    }
    __syncthreads();
    if (w == 0) {
        const float* srcw = red + dg * 64 + eg;
        float* o = kvp + ((size_t)ch * 64 + bh) * 4096 + (size_t)dg * 64 + eg;
#pragma unroll
        for (int rr = 0; rr < 8; ++rr) {
            f32x4 s0 = acc[rr][0] + *(const f32x4*)(srcw + rr * 64);
            f32x4 s1 = acc[rr][1] + *(const f32x4*)(srcw + rr * 64 + 4);
            *(f32x4*)(o + rr * 64)     = s0;
            *(f32x4*)(o + rr * 64 + 4) = s1;
        }
    }
}

__global__ __launch_bounds__(256)
void kv_reduce(const float* __restrict__ kvp, __bf16* __restrict__ kvT)
{
    const int idx = blockIdx.x * 256 + threadIdx.x;
    const int bh  = idx >> 12;
    const int rem = idx & 4095;
    const int d = rem >> 6, e = rem & 63;
    float s = 0.f;
#pragma unroll
    for (int c = 0; c < 4; ++c) s += kvp[((size_t)c * 64 + bh) * 4096 + rem];
    kvT[(size_t)bh * 4096 + e * 64 + d] = (__bf16)(s * 0.125f);
}

// ---------------------------------------------------------------------------
// att + residual + LayerNorm (r13-verified f32-dec residual)
// ---------------------------------------------------------------------------
__global__ __launch_bounds__(256)
void att_ln(const __bf16* __restrict__ Q, const __bf16* __restrict__ kvT,
            const float* __restrict__ dec, const float* __restrict__ gamma,
            const float* __restrict__ beta, float* __restrict__ out)
{
    __shared__ __align__(16) __bf16 att_s[32][1032];

    const int tid  = threadIdx.x;
    const int lane = tid & 63;
    const int w    = tid >> 6;
    const int l4   = lane & 15, g4 = lane >> 4;
    const int t0   = blockIdx.x * 32;
    const int b    = t0 >> 11;

#pragma unroll
    for (int i = 0; i < 4; ++i) {
        const int h = w * 4 + i;
        f32x4 acc[2][4] = {};
#pragma unroll
        for (int kk = 0; kk < 2; ++kk) {
            bf16x8 a0 = *(const bf16x8*)&Q[(size_t)(t0 + l4) * DMODEL + h * 64 + kk * 32 + g4 * 8];
            bf16x8 a1 = *(const bf16x8*)&Q[(size_t)(t0 + 16 + l4) * DMODEL + h * 64 + kk * 32 + g4 * 8];
#pragma unroll
            for (int n = 0; n < 4; ++n) {
                bf16x8 bb = *(const bf16x8*)&kvT[(size_t)(b * 16 + h) * 4096 + (n * 16 + l4) * 64 + kk * 32 + g4 * 8];
                acc[0][n] = __builtin_amdgcn_mfma_f32_16x16x32_bf16(a0, bb, acc[0][n], 0, 0, 0);
                acc[1][n] = __builtin_amdgcn_mfma_f32_16x16x32_bf16(a1, bb, acc[1][n], 0, 0, 0);
            }
        }
#pragma unroll
        for (int m = 0; m < 2; ++m)
#pragma unroll
            for (int n = 0; n < 4; ++n)
#pragma unroll
                for (int j = 0; j < 4; ++j)
                    att_s[m * 16 + g4 * 4 + j][h * 64 + n * 16 + l4] = (__bf16)acc[m][n][j];
    }
    __syncthreads();

    const int rr = tid >> 3, seg = tid & 7;
    const size_t grow = (size_t)t0 + rr;
    float sum = 0.f, ss2 = 0.f;
#pragma unroll
    for (int i = 0; i < 16; ++i) {
        const int c0 = seg * 8 + i * 64;
        bf16x8 av = *(const bf16x8*)&att_s[rr][c0];
        f32x4 d0 = *(const f32x4*)&dec[grow * DMODEL + c0];
        f32x4 d1 = *(const f32x4*)&dec[grow * DMODEL + c0 + 4];
        bf16x8 xs;
#pragma unroll
        for (int j = 0; j < 4; ++j) {
            const float x0 = (float)av[j] + d0[j];
            const float x1 = (float)av[j + 4] + d1[j];
            sum += x0 + x1; ss2 += x0 * x0 + x1 * x1;
            xs[j] = (__bf16)x0; xs[j + 4] = (__bf16)x1;
        }
        *(bf16x8*)&att_s[rr][c0] = xs;
    }
    sum += __shfl_xor(sum, 1); ss2 += __shfl_xor(ss2, 1);
    sum += __shfl_xor(sum, 2); ss2 += __shfl_xor(ss2, 2);
    sum += __shfl_xor(sum, 4); ss2 += __shfl_xor(ss2, 4);
    const float mu   = sum * (1.f / 1024.f);
    const float var  = ss2 * (1.f / 1024.f) - mu * mu;
    const float rstd = rsqrtf(var + 1e-5f);

#pragma unroll
    for (int i = 0; i < 16; ++i) {
        const int c0 = seg * 8 + i * 64;
        bf16x8 xv = *(const bf16x8*)&att_s[rr][c0];
        f32x4 g0 = *(const f32x4*)&gamma[c0];
        f32x4 g1 = *(const f32x4*)&gamma[c0 + 4];
        f32x4 b0 = *(const f32x4*)&beta[c0];
        f32x4 b1 = *(const f32x4*)&beta[c0 + 4];
        f32x4 y0, y1;
#pragma unroll
        for (int j = 0; j < 4; ++j) {
            y0[j] = ((float)xv[j]     - mu) * rstd * g0[j] + b0[j];
            y1[j] = ((float)xv[j + 4] - mu) * rstd * g1[j] + b1[j];
        }
        *(f32x4*)&out[grow * DMODEL + c0]     = y0;
        *(f32x4*)&out[grow * DMODEL + c0 + 4] = y1;
    }
}

// ---------------------------------------------------------------------------
extern "C" void kernel_launch(void* const* d_in, const int* in_sizes, int n_in,
                              void* d_out, int out_size, void* d_ws, size_t ws_size,
                              hipStream_t stream)
{
    const float* enc   = (const float*)d_in[0];
    const float* dec   = (const float*)d_in[1];
    const float* Wq    = (const float*)d_in[2];
    const float* bq    = (const float*)d_in[3];
    const float* Wk    = (const float*)d_in[4];
    const float* bk    = (const float*)d_in[5];
    const float* Wv    = (const float*)d_in[6];
    const float* bv    = (const float*)d_in[7];
    const float* gamma = (const float*)d_in[8];
    const float* beta  = (const float*)d_in[9];

    char* ws = (char*)d_ws;
    __bf16* Qb  = (__bf16*)(ws + QB_OFF);
    __bf16* Kb  = (__bf16*)(ws + KB_OFF);
    __bf16* Vb  = (__bf16*)(ws + VB_OFF);
    float*  kvp = (float*) (ws + KVP_OFF);
    __bf16* WB  = (__bf16*)(ws + WB_OFF);
    __bf16* kvT = (__bf16*)(ws + KVT_OFF);

    conv_w<<<1536, 256, 0, stream>>>(Wq, Wk, Wv, WB);
    qkv_gemm<<<768, 512, 0, stream>>>(dec, enc, WB, bq, bk, bv, Qb, Kb, Vb);
    kv_mm<<<dim3(64, 4), 256, 0, stream>>>(Kb, Vb, kvp);
    kv_reduce<<<1024, 256, 0, stream>>>(kvp, kvT);
    att_ln<<<256, 256, 0, stream>>>(Qb, kvT, dec, gamma, beta, (float*)d_out);
}

// Round 16
// 123.371 us; speedup vs baseline: 1.0477x; 1.0477x over previous
//
#include <hip/hip_runtime.h>
#include <hip/hip_bf16.h>
#include <stdint.h>
#include <stddef.h>

typedef __attribute__((ext_vector_type(8))) __bf16 bf16x8;
typedef __attribute__((ext_vector_type(4))) float f32x4;

#define DMODEL 1024
#define HEADS  16
#define BATCH  4
#define TSEQ   2048
#define MROWS  (BATCH * TSEQ)   // 8192
#define NE     (MROWS * DMODEL) // 8388608
#define NW     (DMODEL * DMODEL)

#define MiB (size_t)1048576
// layout (86.5 MiB peak). kvp (4 MiB) aliases encB (dead after qkv_gemm);
// decB stays LIVE through att_ln (bf16 residual source).
#define QB_OFF   ((size_t)0)          // 16 MiB bf16
#define KB_OFF   (16 * MiB)           // 16 MiB bf16
#define VB_OFF   (32 * MiB)           // 16 MiB bf16
#define ENC_OFF  (48 * MiB)           // 16 MiB bf16
#define KVP_OFF  (48 * MiB)           // 4 MiB f32 (aliases encB)
#define DEC_OFF  (64 * MiB)           // 16 MiB bf16 (live till end)
#define WB_OFF   (80 * MiB)           // 6 MiB bf16
#define KVT_OFF  (86 * MiB)           // 512 KiB bf16

// ---------------------------------------------------------------------------
// one-shot f32 -> bf16: enc, dec, Wq, Wk, Wv. Runs at HBM BW (~18us) with
// ZERO coupling to the GEMM critical path — r5/r11/r15 proved any attempt
// to fold this conversion into the GEMM (stage-side or read-side) costs
// ~25us on the LDS/issue critical path and loses net.
// ---------------------------------------------------------------------------
__global__ __launch_bounds__(256)
void conv_all(const float* __restrict__ enc, const float* __restrict__ dec,
              const float* __restrict__ Wq, const float* __restrict__ Wk,
              const float* __restrict__ Wv,
              __bf16* __restrict__ encB, __bf16* __restrict__ decB,
              __bf16* __restrict__ WB)
{
    const int i = (blockIdx.x * 256 + threadIdx.x) * 8;
    const float* src;
    __bf16* dst;
    int off;
    if (i < NE)            { src = enc; dst = encB; off = i; }
    else if (i < 2 * NE)   { src = dec; dst = decB; off = i - NE; }
    else {
        const int j = i - 2 * NE;
        const int sel = j >> 20;
        off = j & (NW - 1);
        src = (sel == 0) ? Wq : (sel == 1) ? Wk : Wv;
        dst = WB + (size_t)sel * NW;
    }
    f32x4 a = *(const f32x4*)(src + off);
    f32x4 b = *(const f32x4*)(src + off + 4);
    bf16x8 o;
#pragma unroll
    for (int j = 0; j < 4; ++j) { o[j] = (__bf16)a[j]; o[j + 4] = (__bf16)b[j]; }
    *(bf16x8*)(dst + off) = o;
}

// ---------------------------------------------------------------------------
// Fused QKV GEMM — r9/r14 measured-best (69.5us, ~740 TF). BM=128, BN=256,
// BK=64, 8 waves (2Mx4N), merged K-tile phases, grid 768 = 8 slabs x
// (8 bm x 12 (sel,bn)) = 3 exact CU rounds. LDS 96 KiB. 16 ds_read_b128 ->
// 32 MFMA per wave-phase; counted VMW(6); double-barrier KPHASE. T1 slab +
// T2 swizzle (conflicts=0) + T5 setprio. Family floor established over 7
// structural variants (r7-r15: 69-99us); banked.
// ---------------------------------------------------------------------------
__device__ __forceinline__ bf16x8 frag(const __bf16* reg, int rowl, int kh, int g4)
{
    const int slot = ((kh << 2) + g4) ^ (rowl & 7);
    return *(const bf16x8*)(reg + rowl * 64 + slot * 8);
}

__device__ __forceinline__ void stage_half(const __bf16* gbase, int kt,
                                           __bf16* reg, int tid)
{
#pragma unroll
    for (int p = 0; p < 2; ++p) {
        const int c = tid + p * 512;
        const int row = c >> 3, slot = c & 7;
        const __bf16* src = gbase + (size_t)row * DMODEL + kt * 64
                            + ((slot ^ (row & 7)) << 3);
        __builtin_amdgcn_global_load_lds(
            (const __attribute__((address_space(1))) void*)src,
            (__attribute__((address_space(3))) void*)(reg + c * 8), 16, 0, 0);
    }
}

#define VMW(N)  asm volatile("s_waitcnt vmcnt(" #N ")" ::: "memory")
#define LGKM0() asm volatile("s_waitcnt lgkmcnt(0)" ::: "memory")

#define KPHASE(PAR, STAGE_CODE, WAIT_CODE)                                    \
  {                                                                           \
    bf16x8 af[4][2], bfv[4][2];                                               \
    _Pragma("unroll") for (int mf = 0; mf < 4; ++mf)                          \
      _Pragma("unroll") for (int kh = 0; kh < 2; ++kh)                        \
        af[mf][kh] = frag(&ldsA[(PAR) * 8192], wm * 64 + mf * 16 + l4, kh, g4); \
    _Pragma("unroll") for (int nf = 0; nf < 4; ++nf)                          \
      _Pragma("unroll") for (int kh = 0; kh < 2; ++kh)                        \
        bfv[nf][kh] = frag(&ldsB[(PAR) * 16384 + bh2 * 8192],                 \
                           (wn & 1) * 64 + nf * 16 + l4, kh, g4);             \
    LGKM0();                                                                  \
    __builtin_amdgcn_sched_barrier(0);                                        \
    __builtin_amdgcn_s_barrier();                                             \
    STAGE_CODE;                                                               \
    __builtin_amdgcn_sched_barrier(0);                                        \
    __builtin_amdgcn_s_setprio(1);                                            \
    _Pragma("unroll") for (int mf = 0; mf < 4; ++mf)                          \
      _Pragma("unroll") for (int nf = 0; nf < 4; ++nf)                        \
        _Pragma("unroll") for (int kh = 0; kh < 2; ++kh)                      \
          acc[mf][nf] = __builtin_amdgcn_mfma_f32_16x16x32_bf16(              \
              af[mf][kh], bfv[nf][kh], acc[mf][nf], 0, 0, 0);                 \
    __builtin_amdgcn_s_setprio(0);                                            \
    WAIT_CODE;                                                                \
    __builtin_amdgcn_s_barrier();                                             \
  }

__global__ __launch_bounds__(512, 2)
void qkv_gemm(const __bf16* __restrict__ decB, const __bf16* __restrict__ encB,
              const __bf16* __restrict__ WB,
              const float* __restrict__ bq, const float* __restrict__ bk,
              const float* __restrict__ bv,
              __bf16* __restrict__ Qb, __bf16* __restrict__ Kb,
              __bf16* __restrict__ Vb)
{
    __shared__ __align__(16) __bf16 ldsA[2 * 8192];
    __shared__ __align__(16) __bf16 ldsB[2 * 16384];

    const int tid  = threadIdx.x;
    const int lane = tid & 63;
    const int wv   = tid >> 6;
    const int wm   = wv >> 2;
    const int wn   = wv & 3;
    const int bh2  = wn >> 1;
    const int l4   = lane & 15;
    const int g4   = lane >> 4;

    const int bid  = blockIdx.x;
    const int slab = bid & 7;
    const int idx  = bid >> 3;
    const int r    = idx >> 3;
    const int sel  = r >> 2;
    const int bn   = r & 3;
    const int bm   = slab * 8 + (idx & 7);

    const __bf16* A    = (sel == 0) ? decB : encB;
    const __bf16* Wb   = WB + (size_t)sel * NW + (size_t)(bn * 256) * DMODEL;
    const float*  bias = (sel == 0) ? bq : (sel == 1) ? bk : bv;
    __bf16*       C    = (sel == 0) ? Qb : (sel == 1) ? Kb : Vb;

    const __bf16* Ab = A + (size_t)(bm * 128) * DMODEL;

    auto stage_tile = [&](int par, int kt) {
        stage_half(Ab,                        kt, ldsA + par * 8192,         tid);
        stage_half(Wb,                        kt, ldsB + par * 16384,        tid);
        stage_half(Wb + (size_t)128 * DMODEL, kt, ldsB + par * 16384 + 8192, tid);
    };

    f32x4 acc[4][4] = {};

    stage_tile(0, 0);
    stage_tile(1, 1);
    VMW(6);
    __builtin_amdgcn_sched_barrier(0);
    __builtin_amdgcn_s_barrier();

    for (int i = 0; i < 8; ++i) {      // 16 K-tiles, 2 per iter
        KPHASE(0, { if (i < 7) stage_tile(0, 2 * i + 2); },
                  { if (i < 7) { VMW(6); } else { VMW(0); } })
        KPHASE(1, { if (i < 7) stage_tile(1, 2 * i + 3); },
                  { if (i < 7) { VMW(6); } else { VMW(0); } })
    }

#pragma unroll
    for (int mf = 0; mf < 4; ++mf)
#pragma unroll
        for (int nf = 0; nf < 4; ++nf) {
            const int gm0 = bm * 128 + wm * 64 + mf * 16 + g4 * 4;
            const int gn  = bn * 256 + wn * 64 + nf * 16 + l4;
            const float bv2 = bias[gn];
#pragma unroll
            for (int j = 0; j < 4; ++j)
                C[(size_t)(gm0 + j) * DMODEL + gn] =
                    (__bf16)(acc[mf][nf][j] + bv2);
        }
}

// ---------------------------------------------------------------------------
// kv partials + in-block cross-wave reduction (r14-verified): one partial
// per block -> kvp 4 MiB (was 16), -24 MiB round-trip vs r9.
// ---------------------------------------------------------------------------
__global__ __launch_bounds__(256)
void kv_mm(const __bf16* __restrict__ Kb, const __bf16* __restrict__ Vb,
           float* __restrict__ kvp)
{
    __shared__ __align__(16) float Ks[128][64];
    __shared__ __align__(16) float Vs[128][64];

    const int tid = threadIdx.x;
    const int bh  = blockIdx.x;
    const int ch  = blockIdx.y;
    const int b   = bh >> 4, h = bh & 15;
    const int w   = tid >> 6, lane = tid & 63;
    const int dg  = (lane >> 3) * 8;
    const int eg  = (lane & 7) * 8;
    const size_t base = (size_t)b * TSEQ + (size_t)ch * 512;

    f32x4 acc[8][2] = {};

    for (int ss = 0; ss < 4; ++ss) {
        __syncthreads();
#pragma unroll
        for (int i = 0; i < 4; ++i) {
            const int e = i * 2048 + tid * 8;
            const int t = e >> 6, d = e & 63;
            bf16x8 k8 = *(const bf16x8*)&Kb[(base + ss * 128 + t) * DMODEL + h * 64 + d];
            bf16x8 v8 = *(const bf16x8*)&Vb[(base + ss * 128 + t) * DMODEL + h * 64 + d];
            f32x4 kf0, kf1, vf0, vf1;
#pragma unroll
            for (int j = 0; j < 4; ++j) {
                kf0[j] = (float)k8[j]; kf1[j] = (float)k8[j + 4];
                vf0[j] = (float)v8[j]; vf1[j] = (float)v8[j + 4];
            }
            *(f32x4*)&Ks[t][d]     = kf0;
            *(f32x4*)&Ks[t][d + 4] = kf1;
            *(f32x4*)&Vs[t][d]     = vf0;
            *(f32x4*)&Vs[t][d + 4] = vf1;
        }
        __syncthreads();

#pragma unroll 4
        for (int tt = 0; tt < 32; ++tt) {
            const int t = w * 32 + tt;
            f32x4 kd0 = *(const f32x4*)&Ks[t][dg];
            f32x4 kd1 = *(const f32x4*)&Ks[t][dg + 4];
            f32x4 ve0 = *(const f32x4*)&Vs[t][eg];
            f32x4 ve1 = *(const f32x4*)&Vs[t][eg + 4];
#pragma unroll
            for (int rr = 0; rr < 8; ++rr) {
                const float kd = (rr < 4) ? kd0[rr] : kd1[rr - 4];
                acc[rr][0] += ve0 * kd;
                acc[rr][1] += ve1 * kd;
            }
        }
    }

    float* red = &Ks[0][0];                       // 32 KiB scratch
    __syncthreads();
    if (w >= 2) {
        float* dstw = red + (w - 2) * 4096 + dg * 64 + eg;
#pragma unroll
        for (int rr = 0; rr < 8; ++rr) {
            *(f32x4*)(dstw + rr * 64)     = acc[rr][0];
            *(f32x4*)(dstw + rr * 64 + 4) = acc[rr][1];
        }
    }
    __syncthreads();
    if (w < 2) {
        const float* srcw = red + w * 4096 + dg * 64 + eg;
#pragma unroll
        for (int rr = 0; rr < 8; ++rr) {
            acc[rr][0] += *(const f32x4*)(srcw + rr * 64);
            acc[rr][1] += *(const f32x4*)(srcw + rr * 64 + 4);
        }
    }
    __syncthreads();
    if (w == 1) {
        float* dstw = red + dg * 64 + eg;
#pragma unroll
        for (int rr = 0; rr < 8; ++rr) {
            *(f32x4*)(dstw + rr * 64)     = acc[rr][0];
            *(f32x4*)(dstw + rr * 64 + 4) = acc[rr][1];
        }
    }
    __syncthreads();
    if (w == 0) {
        const float* srcw = red + dg * 64 + eg;
        float* o = kvp + ((size_t)ch * 64 + bh) * 4096 + (size_t)dg * 64 + eg;
#pragma unroll
        for (int rr = 0; rr < 8; ++rr) {
            f32x4 s0 = acc[rr][0] + *(const f32x4*)(srcw + rr * 64);
            f32x4 s1 = acc[rr][1] + *(const f32x4*)(srcw + rr * 64 + 4);
            *(f32x4*)(o + rr * 64)     = s0;
            *(f32x4*)(o + rr * 64 + 4) = s1;
        }
    }
}

// ---------------------------------------------------------------------------
// reduce 4 partials; kvT[bh][e][d] = scale * sum_c kvp  (e-major for att B)
// ---------------------------------------------------------------------------
__global__ __launch_bounds__(256)
void kv_reduce(const float* __restrict__ kvp, __bf16* __restrict__ kvT)
{
    const int idx = blockIdx.x * 256 + threadIdx.x;
    const int bh  = idx >> 12;
    const int rem = idx & 4095;
    const int d = rem >> 6, e = rem & 63;
    float s = 0.f;
#pragma unroll
    for (int c = 0; c < 4; ++c) s += kvp[((size_t)c * 64 + bh) * 4096 + rem];
    kvT[(size_t)bh * 4096 + e * 64 + d] = (__bf16)(s * 0.125f);   // 1/sqrt(64)
}

// ---------------------------------------------------------------------------
// att + residual + LayerNorm. Residual from decB (bf16, 16 MB — r14-verified
// absmax-neutral vs f32 dec).
// ---------------------------------------------------------------------------
__global__ __launch_bounds__(256)
void att_ln(const __bf16* __restrict__ Q, const __bf16* __restrict__ kvT,
            const __bf16* __restrict__ decB, const float* __restrict__ gamma,
            const float* __restrict__ beta, float* __restrict__ out)
{
    __shared__ __align__(16) __bf16 att_s[32][1032];

    const int tid  = threadIdx.x;
    const int lane = tid & 63;
    const int w    = tid >> 6;
    const int l4   = lane & 15, g4 = lane >> 4;
    const int t0   = blockIdx.x * 32;
    const int b    = t0 >> 11;

#pragma unroll
    for (int i = 0; i < 4; ++i) {
        const int h = w * 4 + i;
        f32x4 acc[2][4] = {};
#pragma unroll
        for (int kk = 0; kk < 2; ++kk) {
            bf16x8 a0 = *(const bf16x8*)&Q[(size_t)(t0 + l4) * DMODEL + h * 64 + kk * 32 + g4 * 8];
            bf16x8 a1 = *(const bf16x8*)&Q[(size_t)(t0 + 16 + l4) * DMODEL + h * 64 + kk * 32 + g4 * 8];
#pragma unroll
            for (int n = 0; n < 4; ++n) {
                bf16x8 bb = *(const bf16x8*)&kvT[(size_t)(b * 16 + h) * 4096 + (n * 16 + l4) * 64 + kk * 32 + g4 * 8];
                acc[0][n] = __builtin_amdgcn_mfma_f32_16x16x32_bf16(a0, bb, acc[0][n], 0, 0, 0);
                acc[1][n] = __builtin_amdgcn_mfma_f32_16x16x32_bf16(a1, bb, acc[1][n], 0, 0, 0);
            }
        }
#pragma unroll
        for (int m = 0; m < 2; ++m)
#pragma unroll
            for (int n = 0; n < 4; ++n)
#pragma unroll
                for (int j = 0; j < 4; ++j)
                    att_s[m * 16 + g4 * 4 + j][h * 64 + n * 16 + l4] = (__bf16)acc[m][n][j];
    }
    __syncthreads();

    const int rr = tid >> 3, seg = tid & 7;
    const size_t grow = (size_t)t0 + rr;
    float sum = 0.f, ss2 = 0.f;
#pragma unroll
    for (int i = 0; i < 16; ++i) {
        const int c0 = seg * 8 + i * 64;
        bf16x8 av = *(const bf16x8*)&att_s[rr][c0];
        bf16x8 dv = *(const bf16x8*)&decB[grow * DMODEL + c0];
        bf16x8 xs;
#pragma unroll
        for (int j = 0; j < 8; ++j) {
            const float x = (float)av[j] + (float)dv[j];
            sum += x; ss2 += x * x;
            xs[j] = (__bf16)x;
        }
        *(bf16x8*)&att_s[rr][c0] = xs;
    }
    sum += __shfl_xor(sum, 1); ss2 += __shfl_xor(ss2, 1);
    sum += __shfl_xor(sum, 2); ss2 += __shfl_xor(ss2, 2);
    sum += __shfl_xor(sum, 4); ss2 += __shfl_xor(ss2, 4);
    const float mu   = sum * (1.f / 1024.f);
    const float var  = ss2 * (1.f / 1024.f) - mu * mu;
    const float rstd = rsqrtf(var + 1e-5f);

#pragma unroll
    for (int i = 0; i < 16; ++i) {
        const int c0 = seg * 8 + i * 64;
        bf16x8 xv = *(const bf16x8*)&att_s[rr][c0];
        f32x4 g0 = *(const f32x4*)&gamma[c0];
        f32x4 g1 = *(const f32x4*)&gamma[c0 + 4];
        f32x4 b0 = *(const f32x4*)&beta[c0];
        f32x4 b1 = *(const f32x4*)&beta[c0 + 4];
        f32x4 y0, y1;
#pragma unroll
        for (int j = 0; j < 4; ++j) {
            y0[j] = ((float)xv[j]     - mu) * rstd * g0[j] + b0[j];
            y1[j] = ((float)xv[j + 4] - mu) * rstd * g1[j] + b1[j];
        }
        *(f32x4*)&out[grow * DMODEL + c0]     = y0;
        *(f32x4*)&out[grow * DMODEL + c0 + 4] = y1;
    }
}

// ---------------------------------------------------------------------------
extern "C" void kernel_launch(void* const* d_in, const int* in_sizes, int n_in,
                              void* d_out, int out_size, void* d_ws, size_t ws_size,
                              hipStream_t stream)
{
    const float* enc   = (const float*)d_in[0];
    const float* dec   = (const float*)d_in[1];
    const float* Wq    = (const float*)d_in[2];
    const float* bq    = (const float*)d_in[3];
    const float* Wk    = (const float*)d_in[4];
    const float* bk    = (const float*)d_in[5];
    const float* Wv    = (const float*)d_in[6];
    const float* bv    = (const float*)d_in[7];
    const float* gamma = (const float*)d_in[8];
    const float* beta  = (const float*)d_in[9];

    char* ws = (char*)d_ws;
    __bf16* Qb   = (__bf16*)(ws + QB_OFF);
    __bf16* Kb   = (__bf16*)(ws + KB_OFF);
    __bf16* Vb   = (__bf16*)(ws + VB_OFF);
    __bf16* encB = (__bf16*)(ws + ENC_OFF);
    float*  kvp  = (float*) (ws + KVP_OFF);   // aliases encB (dead after gemm)
    __bf16* decB = (__bf16*)(ws + DEC_OFF);   // LIVE till att_ln
    __bf16* WB   = (__bf16*)(ws + WB_OFF);
    __bf16* kvT  = (__bf16*)(ws + KVT_OFF);

    conv_all<<<9728, 256, 0, stream>>>(enc, dec, Wq, Wk, Wv, encB, decB, WB);
    qkv_gemm<<<768, 512, 0, stream>>>(decB, encB, WB, bq, bk, bv, Qb, Kb, Vb);
    kv_mm<<<dim3(64, 4), 256, 0, stream>>>(Kb, Vb, kvp);
    kv_reduce<<<1024, 256, 0, stream>>>(kvp, kvT);
    att_ln<<<256, 256, 0, stream>>>(Qb, kvT, decB, gamma, beta, (float*)d_out);
}